// Round 4
// baseline (74.516 us; speedup 1.0000x reference)
//
#include <hip/hip_runtime.h>
#include <hip/hip_bf16.h>

// GAT layer, N=4096, C_IN=C_OUT=256, HEADS=4, C_HEAD=64.
// Pipeline:
//  K1: h = X @ W^T + b          (bf16 MFMA, fp32 out, 4 MB ws)
//  K2a: e_src/e_dst (x log2e)   (fp32, 16 KB each)
//  K2b: hB = h in MFMA-B-fragment order, bf16 (2 MB)
//  K3: masked softmax (fixed m=0, no online max) + P@H; 4 j-splits merged
//      through LDS inside the block; writes final out. No merge kernel.
// Workspace: ~6.2 MB.

#define NN 4096
#define LOG2E 1.4426950408889634f
#define NEGBIG -1.0e9f

typedef float f32x4 __attribute__((ext_vector_type(4)));
typedef int i32x4 __attribute__((ext_vector_type(4)));
typedef unsigned short u16x8 __attribute__((ext_vector_type(8)));
typedef __bf16 bf16x8 __attribute__((ext_vector_type(8)));

__device__ __forceinline__ unsigned short f2bf_rne(float f) {
    unsigned int u = __builtin_bit_cast(unsigned int, f);
    u += 0x7fffu + ((u >> 16) & 1u);
    return (unsigned short)(u >> 16);
}

__device__ __forceinline__ bf16x8 ld_cvt8(const float* __restrict__ p) {
    f32x4 x = *(const f32x4*)p;
    f32x4 y = *(const f32x4*)(p + 4);
    u16x8 u;
    u[0] = f2bf_rne(x[0]); u[1] = f2bf_rne(x[1]); u[2] = f2bf_rne(x[2]); u[3] = f2bf_rne(x[3]);
    u[4] = f2bf_rne(y[0]); u[5] = f2bf_rne(y[1]); u[6] = f2bf_rne(y[2]); u[7] = f2bf_rne(y[3]);
    return __builtin_bit_cast(bf16x8, u);
}

// ---------------- K1: h = X @ W^T + bias (fp32 out) ----------------
// 256 blocks x 256 thr. Block covers 16 rows; wave w covers cols [64w,64w+64).
__global__ __launch_bounds__(256) void k1_gemm(const float* __restrict__ X,
                                               const float* __restrict__ W,
                                               const float* __restrict__ bias,
                                               float* __restrict__ h) {
    const int lane = threadIdx.x & 63;
    const int wv   = threadIdx.x >> 6;      // 0..3 column group
    const int row  = lane & 15;
    const int kg   = lane >> 4;
    const int rowbase = blockIdx.x * 16;
    const int colbase = wv * 64;

    f32x4 acc0[4];
#pragma unroll
    for (int n = 0; n < 4; ++n) acc0[n] = (f32x4)0.f;

#pragma unroll
    for (int kk = 0; kk < 8; ++kk) {
        const int kb = kk * 32 + kg * 8;
        bf16x8 a0 = ld_cvt8(X + (rowbase + row) * 256 + kb);
#pragma unroll
        for (int n = 0; n < 4; ++n) {
            bf16x8 bb = ld_cvt8(W + (colbase + n * 16 + row) * 256 + kb);
            acc0[n] = __builtin_amdgcn_mfma_f32_16x16x32_bf16(a0, bb, acc0[n], 0, 0, 0);
        }
    }
#pragma unroll
    for (int n = 0; n < 4; ++n) {
        const int col = colbase + n * 16 + row;
        const float bv = bias[col];
#pragma unroll
        for (int r = 0; r < 4; ++r)
            h[(rowbase + 4 * kg + r) * 256 + col] = acc0[n][r] + bv;
    }
}

// ---------------- K2a: e_src/e_dst (scaled by log2e) ----------------
// 1024 blocks x 256 thr; one wave per node row.
__global__ __launch_bounds__(256) void k2_edges(const float* __restrict__ h,
                                                const float* __restrict__ a,
                                                float* __restrict__ esrc,
                                                float* __restrict__ edst) {
    const int lane = threadIdx.x & 63;
    const int r = blockIdx.x * 4 + (threadIdx.x >> 6);
    const int head = lane >> 4;
    const int off = (lane & 15) * 4;
    f32x4 hv = *(const f32x4*)(h + r * 256 + lane * 4);
    f32x4 as = *(const f32x4*)(a + head * 128 + off);
    f32x4 ad = *(const f32x4*)(a + head * 128 + 64 + off);
    float es = hv[0] * as[0] + hv[1] * as[1] + hv[2] * as[2] + hv[3] * as[3];
    float ed = hv[0] * ad[0] + hv[1] * ad[1] + hv[2] * ad[2] + hv[3] * ad[3];
#pragma unroll
    for (int d = 1; d < 16; d <<= 1) {
        es += __shfl_xor(es, d);
        ed += __shfl_xor(ed, d);
    }
    if ((lane & 15) == 0) {
        esrc[head * NN + r] = es * LOG2E;
        edst[head * NN + r] = ed * LOG2E;
    }
}

// ---------------- K2b: build hB in B-fragment order (bf16) ----------------
// hB[(((h*128 + t)*4 + n)*64 + lane)*8 + e] = h[t*32 + 8*(lane>>4)+e][h*64 + 16n + (lane&15)]
__global__ __launch_bounds__(256) void k2_swizzle(const float* __restrict__ h,
                                                  unsigned short* __restrict__ hB) {
    const int gid = blockIdx.x * 256 + threadIdx.x;  // 131072 total
    const int lane = gid & 63;
    const int n  = (gid >> 6) & 3;
    const int t  = (gid >> 8) & 127;
    const int hh = (gid >> 15) & 3;
    const int jb = t * 32 + (lane >> 4) * 8;
    const int c  = hh * 64 + n * 16 + (lane & 15);
    u16x8 u;
#pragma unroll
    for (int e = 0; e < 8; ++e) u[e] = f2bf_rne(h[(jb + e) * 256 + c]);
    *(u16x8*)(hB + ((((hh * 128 + t) * 4 + n) * 64 + lane) * 8)) = u;
}

// ---------------- K3: masked softmax (m=0) + P@H, LDS-merged j-splits ----------------
// grid 512: ib = bx>>1 (16 rows), hb = bx&1 (head pair).
// 8 waves = 4 j-splits (q = w>>1) x 2 heads (hd = w&1). Each wave: 16 rows x 1024 j.
#define K3_LOAD(S, T)                                        \
    A0##S = *(const i32x4*)(aRow + (T) * 32);                \
    A1##S = *(const i32x4*)(aRow + (T) * 32 + 4);            \
    E0##S = *(const f32x4*)(eD + (T) * 32);                  \
    E1##S = *(const f32x4*)(eD + (T) * 32 + 4);              \
    B0##S = *(const u16x8*)(hBp + (T) * 2048);               \
    B1##S = *(const u16x8*)(hBp + (T) * 2048 + 512);         \
    B2##S = *(const u16x8*)(hBp + (T) * 2048 + 1024);        \
    B3##S = *(const u16x8*)(hBp + (T) * 2048 + 1536);

#define K3_COMPUTE(S) {                                                          \
    float s0 = es + E0##S[0], s1 = es + E0##S[1], s2 = es + E0##S[2], s3 = es + E0##S[3]; \
    float s4 = es + E1##S[0], s5 = es + E1##S[1], s6 = es + E1##S[2], s7 = es + E1##S[3]; \
    s0 = fmaxf(s0, 0.2f * s0); s1 = fmaxf(s1, 0.2f * s1);                        \
    s2 = fmaxf(s2, 0.2f * s2); s3 = fmaxf(s3, 0.2f * s3);                        \
    s4 = fmaxf(s4, 0.2f * s4); s5 = fmaxf(s5, 0.2f * s5);                        \
    s6 = fmaxf(s6, 0.2f * s6); s7 = fmaxf(s7, 0.2f * s7);                        \
    s0 = (A0##S[0] != 0) ? s0 : NEGBIG; s1 = (A0##S[1] != 0) ? s1 : NEGBIG;      \
    s2 = (A0##S[2] != 0) ? s2 : NEGBIG; s3 = (A0##S[3] != 0) ? s3 : NEGBIG;      \
    s4 = (A1##S[0] != 0) ? s4 : NEGBIG; s5 = (A1##S[1] != 0) ? s5 : NEGBIG;      \
    s6 = (A1##S[2] != 0) ? s6 : NEGBIG; s7 = (A1##S[3] != 0) ? s7 : NEGBIG;      \
    float p0 = __builtin_exp2f(s0), p1 = __builtin_exp2f(s1);                    \
    float p2 = __builtin_exp2f(s2), p3 = __builtin_exp2f(s3);                    \
    float p4 = __builtin_exp2f(s4), p5 = __builtin_exp2f(s5);                    \
    float p6 = __builtin_exp2f(s6), p7 = __builtin_exp2f(s7);                    \
    bf16x8 af;                                                                   \
    af[0] = (__bf16)p0; af[1] = (__bf16)p1; af[2] = (__bf16)p2; af[3] = (__bf16)p3; \
    af[4] = (__bf16)p4; af[5] = (__bf16)p5; af[6] = (__bf16)p6; af[7] = (__bf16)p7; \
    acc0 = __builtin_amdgcn_mfma_f32_16x16x32_bf16(af, __builtin_bit_cast(bf16x8, B0##S), acc0, 0, 0, 0); \
    acc1 = __builtin_amdgcn_mfma_f32_16x16x32_bf16(af, __builtin_bit_cast(bf16x8, B1##S), acc1, 0, 0, 0); \
    acc2 = __builtin_amdgcn_mfma_f32_16x16x32_bf16(af, __builtin_bit_cast(bf16x8, B2##S), acc2, 0, 0, 0); \
    acc3 = __builtin_amdgcn_mfma_f32_16x16x32_bf16(af, __builtin_bit_cast(bf16x8, B3##S), acc3, 0, 0, 0); \
    acc4 = __builtin_amdgcn_mfma_f32_16x16x32_bf16(af, bOnes, acc4, 0, 0, 0);    \
}

__global__ __launch_bounds__(512, 4) void k3_flash(const int* __restrict__ adj,
                                                   const unsigned short* __restrict__ hB,
                                                   const float* __restrict__ esrc,
                                                   const float* __restrict__ edst,
                                                   float* __restrict__ out) {
    __shared__ float lacc[8][16][64];
    __shared__ float lls[8][16];

    const int lane = threadIdx.x & 63;
    const int w  = threadIdx.x >> 6;  // 0..7
    const int q  = w >> 1;            // j-split 0..3
    const int hd = w & 1;             // head within pair
    const int hb = blockIdx.x & 1;    // head pair
    const int ib = blockIdx.x >> 1;   // 0..255
    const int hh = hb * 2 + hd;
    const int i0 = ib * 16;
    const int row = lane & 15;
    const int kg  = lane >> 4;

    const float es = esrc[hh * NN + i0 + row];
    const int* aRow = adj + (i0 + row) * NN + q * 1024 + kg * 8;
    const float* eD = edst + hh * NN + q * 1024 + kg * 8;
    const unsigned short* hBp = hB + ((hh * 128 + q * 32) * 256 + lane) * 8;

    // ones B-fragment: column 0 only
    u16x8 ou;
    const unsigned short ov = (row == 0) ? (unsigned short)0x3F80 : (unsigned short)0;
#pragma unroll
    for (int e = 0; e < 8; ++e) ou[e] = ov;
    const bf16x8 bOnes = __builtin_bit_cast(bf16x8, ou);

    f32x4 acc0 = (f32x4)0.f, acc1 = (f32x4)0.f, acc2 = (f32x4)0.f,
          acc3 = (f32x4)0.f, acc4 = (f32x4)0.f;

    i32x4 A0a, A1a, A0b, A1b;
    f32x4 E0a, E1a, E0b, E1b;
    u16x8 B0a, B1a, B2a, B3a, B0b, B1b, B2b, B3b;

    K3_LOAD(a, 0)
    for (int t = 0; t < 32; t += 2) {
        K3_LOAD(b, t + 1)
        K3_COMPUTE(a)
        if (t + 2 < 32) { K3_LOAD(a, t + 2) }
        K3_COMPUTE(b)
    }

    // stash wave partials in LDS
#pragma unroll
    for (int n = 0; n < 4; ++n) {
        f32x4 an = (n == 0) ? acc0 : (n == 1) ? acc1 : (n == 2) ? acc2 : acc3;
#pragma unroll
        for (int r = 0; r < 4; ++r)
            lacc[w][kg * 4 + r][n * 16 + row] = an[r];
    }
    if (row == 0) {
#pragma unroll
        for (int r = 0; r < 4; ++r)
            lls[w][kg * 4 + r] = acc4[r];
    }
    __syncthreads();

    // merge 4 j-splits, normalize, write final out
    const int idx = threadIdx.x * 4;   // 0..2047
    const int r2  = idx >> 7;          // row 0..15
    const int c2  = idx & 127;         // col-pair 0..127
    const int hd2 = c2 >> 6;
    const int c   = c2 & 63;
    f32x4 v = (f32x4)0.f;
    float l = 0.f;
#pragma unroll
    for (int q2 = 0; q2 < 4; ++q2) {
        v += *(const f32x4*)&lacc[q2 * 2 + hd2][r2][c];
        l += lls[q2 * 2 + hd2][r2];
    }
    const float inv = 1.f / l;
    f32x4 o;
    o[0] = v[0] * inv; o[1] = v[1] * inv; o[2] = v[2] * inv; o[3] = v[3] * inv;
    *(f32x4*)(out + (i0 + r2) * 256 + hb * 128 + c2) = o;
}

extern "C" void kernel_launch(void* const* d_in, const int* in_sizes, int n_in,
                              void* d_out, int out_size, void* d_ws, size_t ws_size,
                              hipStream_t stream) {
    const float* X    = (const float*)d_in[0];
    const int*   adj  = (const int*)d_in[1];
    const float* W    = (const float*)d_in[2];
    const float* bias = (const float*)d_in[3];
    const float* a    = (const float*)d_in[4];
    float* out = (float*)d_out;

    char* ws = (char*)d_ws;
    float*          h    = (float*)(ws);                                  // 4 MB
    unsigned short* hB   = (unsigned short*)(ws + (4 << 20));             // 2 MB
    float*          esrc = (float*)(ws + (6 << 20));                      // 16 KB
    float*          edst = (float*)(ws + (6 << 20) + (64 << 10));         // 16 KB

    k1_gemm<<<256, 256, 0, stream>>>(X, W, bias, h);
    k2_edges<<<1024, 256, 0, stream>>>(h, a, esrc, edst);
    k2_swizzle<<<512, 256, 0, stream>>>(h, hB);
    k3_flash<<<512, 512, 0, stream>>>(adj, hB, esrc, edst, out);
}

// Round 5
// 70.717 us; speedup vs baseline: 1.0537x; 1.0537x over previous
//
#include <hip/hip_runtime.h>
#include <hip/hip_bf16.h>

// GAT layer, N=4096, C_IN=C_OUT=256, HEADS=4, C_HEAD=64.
// Pipeline:
//  K0: pack adj (64 MB int32 0/1) -> 2 MB bitmask, k3-lane-contiguous layout
//  K1: h = X @ W^T + b          (bf16 MFMA, fp32 out, 4 MB ws)
//  K2a: e_src/e_dst (x log2e)   (fp32, 16 KB each)
//  K2b: hB = h in MFMA-B-fragment order, bf16 (2 MB)
//  K3: masked softmax (fixed m=0) + P@H from bitmask; 4 j-splits merged
//      through LDS inside the block; writes final out.
// Workspace: ~8.2 MB.

#define NN 4096
#define LOG2E 1.4426950408889634f
#define NEGBIG -1.0e9f

typedef float f32x4 __attribute__((ext_vector_type(4)));
typedef int i32x4 __attribute__((ext_vector_type(4)));
typedef unsigned short u16x8 __attribute__((ext_vector_type(8)));
typedef __bf16 bf16x8 __attribute__((ext_vector_type(8)));

__device__ __forceinline__ unsigned short f2bf_rne(float f) {
    unsigned int u = __builtin_bit_cast(unsigned int, f);
    u += 0x7fffu + ((u >> 16) & 1u);
    return (unsigned short)(u >> 16);
}

__device__ __forceinline__ bf16x8 ld_cvt8(const float* __restrict__ p) {
    f32x4 x = *(const f32x4*)p;
    f32x4 y = *(const f32x4*)(p + 4);
    u16x8 u;
    u[0] = f2bf_rne(x[0]); u[1] = f2bf_rne(x[1]); u[2] = f2bf_rne(x[2]); u[3] = f2bf_rne(x[3]);
    u[4] = f2bf_rne(y[0]); u[5] = f2bf_rne(y[1]); u[6] = f2bf_rne(y[2]); u[7] = f2bf_rne(y[3]);
    return __builtin_bit_cast(bf16x8, u);
}

// ---------------- K0: pack adj into k3-layout bitmask ----------------
// mask byte [i*512 + q*128 + kg*32 + t] bit e  <-  adj[i][q*1024 + t*32 + kg*8 + e]
// One thread emits one output dword (4 bytes = tiles t0..t0+3 for one (i,q,kg)).
__global__ __launch_bounds__(256) void k0_pack(const int* __restrict__ adj,
                                               unsigned int* __restrict__ mb) {
    const int od = blockIdx.x * 256 + threadIdx.x;   // 0 .. 524287
    const int i  = od >> 7;
    const int r  = od & 127;
    const int q  = r >> 5;
    const int kg = (r >> 3) & 3;
    const int t0 = (r & 7) * 4;
    const int* src = adj + i * 4096 + q * 1024 + kg * 8;
    unsigned int d = 0;
#pragma unroll
    for (int b = 0; b < 4; ++b) {
        i32x4 v0 = *(const i32x4*)(src + (t0 + b) * 32);
        i32x4 v1 = *(const i32x4*)(src + (t0 + b) * 32 + 4);
#pragma unroll
        for (int e = 0; e < 4; ++e) {
            d |= (unsigned int)(v0[e] & 1) << (b * 8 + e);
            d |= (unsigned int)(v1[e] & 1) << (b * 8 + 4 + e);
        }
    }
    mb[od] = d;
}

// ---------------- K1: h = X @ W^T + bias (fp32 out) ----------------
__global__ __launch_bounds__(256) void k1_gemm(const float* __restrict__ X,
                                               const float* __restrict__ W,
                                               const float* __restrict__ bias,
                                               float* __restrict__ h) {
    const int lane = threadIdx.x & 63;
    const int wv   = threadIdx.x >> 6;      // 0..3 column group
    const int row  = lane & 15;
    const int kg   = lane >> 4;
    const int rowbase = blockIdx.x * 16;
    const int colbase = wv * 64;

    f32x4 acc0[4];
#pragma unroll
    for (int n = 0; n < 4; ++n) acc0[n] = (f32x4)0.f;

#pragma unroll
    for (int kk = 0; kk < 8; ++kk) {
        const int kb = kk * 32 + kg * 8;
        bf16x8 a0 = ld_cvt8(X + (rowbase + row) * 256 + kb);
#pragma unroll
        for (int n = 0; n < 4; ++n) {
            bf16x8 bb = ld_cvt8(W + (colbase + n * 16 + row) * 256 + kb);
            acc0[n] = __builtin_amdgcn_mfma_f32_16x16x32_bf16(a0, bb, acc0[n], 0, 0, 0);
        }
    }
#pragma unroll
    for (int n = 0; n < 4; ++n) {
        const int col = colbase + n * 16 + row;
        const float bv = bias[col];
#pragma unroll
        for (int r = 0; r < 4; ++r)
            h[(rowbase + 4 * kg + r) * 256 + col] = acc0[n][r] + bv;
    }
}

// ---------------- K2a: e_src/e_dst (scaled by log2e) ----------------
__global__ __launch_bounds__(256) void k2_edges(const float* __restrict__ h,
                                                const float* __restrict__ a,
                                                float* __restrict__ esrc,
                                                float* __restrict__ edst) {
    const int lane = threadIdx.x & 63;
    const int r = blockIdx.x * 4 + (threadIdx.x >> 6);
    const int head = lane >> 4;
    const int off = (lane & 15) * 4;
    f32x4 hv = *(const f32x4*)(h + r * 256 + lane * 4);
    f32x4 as = *(const f32x4*)(a + head * 128 + off);
    f32x4 ad = *(const f32x4*)(a + head * 128 + 64 + off);
    float es = hv[0] * as[0] + hv[1] * as[1] + hv[2] * as[2] + hv[3] * as[3];
    float ed = hv[0] * ad[0] + hv[1] * ad[1] + hv[2] * ad[2] + hv[3] * ad[3];
#pragma unroll
    for (int d = 1; d < 16; d <<= 1) {
        es += __shfl_xor(es, d);
        ed += __shfl_xor(ed, d);
    }
    if ((lane & 15) == 0) {
        esrc[head * NN + r] = es * LOG2E;
        edst[head * NN + r] = ed * LOG2E;
    }
}

// ---------------- K2b: build hB in B-fragment order (bf16) ----------------
__global__ __launch_bounds__(256) void k2_swizzle(const float* __restrict__ h,
                                                  unsigned short* __restrict__ hB) {
    const int gid = blockIdx.x * 256 + threadIdx.x;  // 131072 total
    const int lane = gid & 63;
    const int n  = (gid >> 6) & 3;
    const int t  = (gid >> 8) & 127;
    const int hh = (gid >> 15) & 3;
    const int jb = t * 32 + (lane >> 4) * 8;
    const int c  = hh * 64 + n * 16 + (lane & 15);
    u16x8 u;
#pragma unroll
    for (int e = 0; e < 8; ++e) u[e] = f2bf_rne(h[(jb + e) * 256 + c]);
    *(u16x8*)(hB + ((((hh * 128 + t) * 4 + n) * 64 + lane) * 8)) = u;
}

// ---------------- K3: bitmask softmax (m=0) + P@H, LDS-merged j-splits ----------------
// grid 512: ib = bx>>1 (16 rows), hb = bx&1 (head pair).
// 8 waves = 4 j-splits (q = w>>1) x 2 heads (hd = w&1). Each wave: 16 rows x 1024 j.
#define NEGBITS 0xCE6E6B28u   /* bit pattern of -1.0e9f */

#define K3_LOAD(S, T)                                        \
    M##S  = (unsigned int)mrow[(T)];                         \
    E0##S = *(const f32x4*)(eD + (T) * 32);                  \
    E1##S = *(const f32x4*)(eD + (T) * 32 + 4);              \
    B0##S = *(const u16x8*)(hBp + (T) * 2048);               \
    B1##S = *(const u16x8*)(hBp + (T) * 2048 + 512);         \
    B2##S = *(const u16x8*)(hBp + (T) * 2048 + 1024);        \
    B3##S = *(const u16x8*)(hBp + (T) * 2048 + 1536);

#define K3_MASKSEL(p, s, mword, e)                                               \
    {                                                                            \
        unsigned int mf = (unsigned int)((int)((mword) << (31 - (e))) >> 31);    \
        p = __builtin_bit_cast(float,                                            \
              (mf & __builtin_bit_cast(unsigned int, s)) | (~mf & NEGBITS));     \
    }

#define K3_COMPUTE(S) {                                                          \
    float s0 = es + E0##S[0], s1 = es + E0##S[1], s2 = es + E0##S[2], s3 = es + E0##S[3]; \
    float s4 = es + E1##S[0], s5 = es + E1##S[1], s6 = es + E1##S[2], s7 = es + E1##S[3]; \
    s0 = fmaxf(s0, 0.2f * s0); s1 = fmaxf(s1, 0.2f * s1);                        \
    s2 = fmaxf(s2, 0.2f * s2); s3 = fmaxf(s3, 0.2f * s3);                        \
    s4 = fmaxf(s4, 0.2f * s4); s5 = fmaxf(s5, 0.2f * s5);                        \
    s6 = fmaxf(s6, 0.2f * s6); s7 = fmaxf(s7, 0.2f * s7);                        \
    K3_MASKSEL(s0, s0, M##S, 0) K3_MASKSEL(s1, s1, M##S, 1)                      \
    K3_MASKSEL(s2, s2, M##S, 2) K3_MASKSEL(s3, s3, M##S, 3)                      \
    K3_MASKSEL(s4, s4, M##S, 4) K3_MASKSEL(s5, s5, M##S, 5)                      \
    K3_MASKSEL(s6, s6, M##S, 6) K3_MASKSEL(s7, s7, M##S, 7)                      \
    float p0 = __builtin_exp2f(s0), p1 = __builtin_exp2f(s1);                    \
    float p2 = __builtin_exp2f(s2), p3 = __builtin_exp2f(s3);                    \
    float p4 = __builtin_exp2f(s4), p5 = __builtin_exp2f(s5);                    \
    float p6 = __builtin_exp2f(s6), p7 = __builtin_exp2f(s7);                    \
    bf16x8 af;                                                                   \
    af[0] = (__bf16)p0; af[1] = (__bf16)p1; af[2] = (__bf16)p2; af[3] = (__bf16)p3; \
    af[4] = (__bf16)p4; af[5] = (__bf16)p5; af[6] = (__bf16)p6; af[7] = (__bf16)p7; \
    acc0 = __builtin_amdgcn_mfma_f32_16x16x32_bf16(af, __builtin_bit_cast(bf16x8, B0##S), acc0, 0, 0, 0); \
    acc1 = __builtin_amdgcn_mfma_f32_16x16x32_bf16(af, __builtin_bit_cast(bf16x8, B1##S), acc1, 0, 0, 0); \
    acc2 = __builtin_amdgcn_mfma_f32_16x16x32_bf16(af, __builtin_bit_cast(bf16x8, B2##S), acc2, 0, 0, 0); \
    acc3 = __builtin_amdgcn_mfma_f32_16x16x32_bf16(af, __builtin_bit_cast(bf16x8, B3##S), acc3, 0, 0, 0); \
    acc4 = __builtin_amdgcn_mfma_f32_16x16x32_bf16(af, bOnes, acc4, 0, 0, 0);    \
}

__global__ __launch_bounds__(512, 2) void k3_flash(const unsigned char* __restrict__ mbB,
                                                   const unsigned short* __restrict__ hB,
                                                   const float* __restrict__ esrc,
                                                   const float* __restrict__ edst,
                                                   float* __restrict__ out) {
    __shared__ float lacc[8][16][64];
    __shared__ float lls[8][16];

    const int lane = threadIdx.x & 63;
    const int w  = threadIdx.x >> 6;  // 0..7
    const int q  = w >> 1;            // j-split 0..3
    const int hd = w & 1;             // head within pair
    const int hb = blockIdx.x & 1;    // head pair
    const int ib = blockIdx.x >> 1;   // 0..255
    const int hh = hb * 2 + hd;
    const int i0 = ib * 16;
    const int row = lane & 15;
    const int kg  = lane >> 4;

    const float es = esrc[hh * NN + i0 + row];
    const unsigned char* mrow = mbB + (i0 + row) * 512 + q * 128 + kg * 32;
    const float* eD = edst + hh * NN + q * 1024 + kg * 8;
    const unsigned short* hBp = hB + ((hh * 128 + q * 32) * 256 + lane) * 8;

    // ones B-fragment: column 0 only
    u16x8 ou;
    const unsigned short ov = (row == 0) ? (unsigned short)0x3F80 : (unsigned short)0;
#pragma unroll
    for (int e = 0; e < 8; ++e) ou[e] = ov;
    const bf16x8 bOnes = __builtin_bit_cast(bf16x8, ou);

    f32x4 acc0 = (f32x4)0.f, acc1 = (f32x4)0.f, acc2 = (f32x4)0.f,
          acc3 = (f32x4)0.f, acc4 = (f32x4)0.f;

    unsigned int Ma, Mb;
    f32x4 E0a, E1a, E0b, E1b;
    u16x8 B0a, B1a, B2a, B3a, B0b, B1b, B2b, B3b;

    K3_LOAD(a, 0)
    for (int t = 0; t < 32; t += 2) {
        K3_LOAD(b, t + 1)
        K3_COMPUTE(a)
        if (t + 2 < 32) { K3_LOAD(a, t + 2) }
        K3_COMPUTE(b)
    }

    // stash wave partials in LDS
#pragma unroll
    for (int n = 0; n < 4; ++n) {
        f32x4 an = (n == 0) ? acc0 : (n == 1) ? acc1 : (n == 2) ? acc2 : acc3;
#pragma unroll
        for (int r = 0; r < 4; ++r)
            lacc[w][kg * 4 + r][n * 16 + row] = an[r];
    }
    if (row == 0) {
#pragma unroll
        for (int r = 0; r < 4; ++r)
            lls[w][kg * 4 + r] = acc4[r];
    }
    __syncthreads();

    // merge 4 j-splits, normalize, write final out
    const int idx = threadIdx.x * 4;   // 0..2047
    const int r2  = idx >> 7;          // row 0..15
    const int c2  = idx & 127;         // col-pair 0..127
    const int hd2 = c2 >> 6;
    const int c   = c2 & 63;
    f32x4 v = (f32x4)0.f;
    float l = 0.f;
#pragma unroll
    for (int q2 = 0; q2 < 4; ++q2) {
        v += *(const f32x4*)&lacc[q2 * 2 + hd2][r2][c];
        l += lls[q2 * 2 + hd2][r2];
    }
    const float inv = 1.f / l;
    f32x4 o;
    o[0] = v[0] * inv; o[1] = v[1] * inv; o[2] = v[2] * inv; o[3] = v[3] * inv;
    *(f32x4*)(out + (i0 + r2) * 256 + hb * 128 + c2) = o;
}

extern "C" void kernel_launch(void* const* d_in, const int* in_sizes, int n_in,
                              void* d_out, int out_size, void* d_ws, size_t ws_size,
                              hipStream_t stream) {
    const float* X    = (const float*)d_in[0];
    const int*   adj  = (const int*)d_in[1];
    const float* W    = (const float*)d_in[2];
    const float* bias = (const float*)d_in[3];
    const float* a    = (const float*)d_in[4];
    float* out = (float*)d_out;

    char* ws = (char*)d_ws;
    float*          h    = (float*)(ws);                                  // 4 MB
    unsigned short* hB   = (unsigned short*)(ws + (4 << 20));             // 2 MB
    float*          esrc = (float*)(ws + (6 << 20));                      // 16 KB
    float*          edst = (float*)(ws + (6 << 20) + (64 << 10));         // 16 KB
    unsigned int*   mb   = (unsigned int*)(ws + (6 << 20) + (128 << 10)); // 2 MB

    k0_pack<<<2048, 256, 0, stream>>>(adj, mb);
    k1_gemm<<<256, 256, 0, stream>>>(X, W, bias, h);
    k2_edges<<<1024, 256, 0, stream>>>(h, a, esrc, edst);
    k2_swizzle<<<512, 256, 0, stream>>>(h, hB);
    k3_flash<<<512, 512, 0, stream>>>((const unsigned char*)mb, hB, esrc, edst, out);
}

// Round 7
// 59.366 us; speedup vs baseline: 1.2552x; 1.1912x over previous
//
#include <hip/hip_runtime.h>
#include <hip/hip_bf16.h>

// GAT layer, N=4096, C_IN=C_OUT=256, HEADS=4, C_HEAD=64.
// Pipeline (3 kernels):
//  K0: pack adj (64 MB int32 0/1) -> 2 MB bitmask, k3-lane-contiguous layout
//  K1f: h = X@W^T + b computed in-register; writes hB (bf16, MFMA-B-fragment
//       order) + e_src/e_dst (x log2e) directly. h fp32 never materialized.
//  K3: masked softmax (fixed m=0) + P@H from bitmask. 32 i-rows per wave
//      (2 A-fragments share each B load -> halves L2 hB traffic), 8 j-splits
//      merged through LDS (two passes, 33 KB), writes final out.
// Workspace: ~4.2 MB.  (esrc/edst are 64 KB EACH — HEADS*N floats.)

#define NN 4096
#define LOG2E 1.4426950408889634f

typedef float f32x4 __attribute__((ext_vector_type(4)));
typedef int i32x4 __attribute__((ext_vector_type(4)));
typedef unsigned short u16x4 __attribute__((ext_vector_type(4)));
typedef unsigned short u16x8 __attribute__((ext_vector_type(8)));
typedef __bf16 bf16x8 __attribute__((ext_vector_type(8)));

__device__ __forceinline__ unsigned short f2bf_rne(float f) {
    unsigned int u = __builtin_bit_cast(unsigned int, f);
    u += 0x7fffu + ((u >> 16) & 1u);
    return (unsigned short)(u >> 16);
}

__device__ __forceinline__ bf16x8 ld_cvt8(const float* __restrict__ p) {
    f32x4 x = *(const f32x4*)p;
    f32x4 y = *(const f32x4*)(p + 4);
    u16x8 u;
    u[0] = f2bf_rne(x[0]); u[1] = f2bf_rne(x[1]); u[2] = f2bf_rne(x[2]); u[3] = f2bf_rne(x[3]);
    u[4] = f2bf_rne(y[0]); u[5] = f2bf_rne(y[1]); u[6] = f2bf_rne(y[2]); u[7] = f2bf_rne(y[3]);
    return __builtin_bit_cast(bf16x8, u);
}

// ---------------- K0: pack adj into k3-layout bitmask ----------------
// mask byte [i*512 + q0*128 + kg*32 + t0] bit e <- adj[i][q0*1024 + t0*32 + kg*8 + e]
__global__ __launch_bounds__(256) void k0_pack(const int* __restrict__ adj,
                                               unsigned int* __restrict__ mb) {
    const int od = blockIdx.x * 256 + threadIdx.x;   // 0 .. 524287
    const int i  = od >> 7;
    const int r  = od & 127;
    const int q  = r >> 5;
    const int kg = (r >> 3) & 3;
    const int t0 = (r & 7) * 4;
    const int* src = adj + i * 4096 + q * 1024 + kg * 8;
    unsigned int d = 0;
#pragma unroll
    for (int b = 0; b < 4; ++b) {
        i32x4 v0 = *(const i32x4*)(src + (t0 + b) * 32);
        i32x4 v1 = *(const i32x4*)(src + (t0 + b) * 32 + 4);
#pragma unroll
        for (int e = 0; e < 4; ++e) {
            d |= (unsigned int)(v0[e] & 1) << (b * 8 + e);
            d |= (unsigned int)(v1[e] & 1) << (b * 8 + 4 + e);
        }
    }
    mb[od] = d;
}

// ---------------- K1f: fused GEMM + hB-swizzle + e_src/e_dst ----------------
// 256 blocks x 256 thr. Block = 16 rows; wave hh owns cols [64hh,64hh+64) = head hh.
__global__ __launch_bounds__(256) void k1_fused(const float* __restrict__ X,
                                                const float* __restrict__ W,
                                                const float* __restrict__ bias,
                                                const float* __restrict__ a,
                                                unsigned short* __restrict__ hB,
                                                float* __restrict__ esrc,
                                                float* __restrict__ edst) {
    const int lane = threadIdx.x & 63;
    const int hh   = threadIdx.x >> 6;      // head / column group
    const int row  = lane & 15;
    const int kg   = lane >> 4;
    const int rowbase = blockIdx.x * 16;

    f32x4 acc[4];
#pragma unroll
    for (int n = 0; n < 4; ++n) acc[n] = (f32x4)0.f;

#pragma unroll
    for (int kk = 0; kk < 8; ++kk) {
        const int kb = kk * 32 + kg * 8;
        bf16x8 a0 = ld_cvt8(X + (rowbase + row) * 256 + kb);
#pragma unroll
        for (int n = 0; n < 4; ++n) {
            bf16x8 bb = ld_cvt8(W + (hh * 64 + n * 16 + row) * 256 + kb);
            acc[n] = __builtin_amdgcn_mfma_f32_16x16x32_bf16(a0, bb, acc[n], 0, 0, 0);
        }
    }

    // epilogue: bias, hB store (fragment order), e_src/e_dst dots
    // value acc[n][r] = h[rowbase+4kg+r][hh*64 + n*16 + row]
    // -> hB lane' = (rb2*2 + (kg>>1))*16 + row, e = (kg&1)*4 + r
    const int t   = rowbase >> 5;
    const int lp  = (((rowbase >> 4) & 1) * 2 + (kg >> 1)) * 16 + row;
    const int eoff = (kg & 1) * 4;
    unsigned short* hbb = hB + (hh * 128 + t) * 2048 + lp * 8 + eoff;

    float eS0 = 0.f, eS1 = 0.f, eS2 = 0.f, eS3 = 0.f;
    float eT0 = 0.f, eT1 = 0.f, eT2 = 0.f, eT3 = 0.f;
#pragma unroll
    for (int n = 0; n < 4; ++n) {
        const int col = hh * 64 + n * 16 + row;
        const float bv = bias[col];
        f32x4 hv;
        hv[0] = acc[n][0] + bv; hv[1] = acc[n][1] + bv;
        hv[2] = acc[n][2] + bv; hv[3] = acc[n][3] + bv;
        u16x4 us;
        us[0] = f2bf_rne(hv[0]); us[1] = f2bf_rne(hv[1]);
        us[2] = f2bf_rne(hv[2]); us[3] = f2bf_rne(hv[3]);
        *(u16x4*)(hbb + n * 512) = us;
        const float as_ = a[hh * 128 + n * 16 + row];
        const float ad_ = a[hh * 128 + 64 + n * 16 + row];
        eS0 += hv[0] * as_; eS1 += hv[1] * as_; eS2 += hv[2] * as_; eS3 += hv[3] * as_;
        eT0 += hv[0] * ad_; eT1 += hv[1] * ad_; eT2 += hv[2] * ad_; eT3 += hv[3] * ad_;
    }
#pragma unroll
    for (int d = 1; d < 16; d <<= 1) {
        eS0 += __shfl_xor(eS0, d); eS1 += __shfl_xor(eS1, d);
        eS2 += __shfl_xor(eS2, d); eS3 += __shfl_xor(eS3, d);
        eT0 += __shfl_xor(eT0, d); eT1 += __shfl_xor(eT1, d);
        eT2 += __shfl_xor(eT2, d); eT3 += __shfl_xor(eT3, d);
    }
    if (row == 0) {
        const int rb = hh * NN + rowbase + kg * 4;
        esrc[rb + 0] = eS0 * LOG2E; esrc[rb + 1] = eS1 * LOG2E;
        esrc[rb + 2] = eS2 * LOG2E; esrc[rb + 3] = eS3 * LOG2E;
        edst[rb + 0] = eT0 * LOG2E; edst[rb + 1] = eT1 * LOG2E;
        edst[rb + 2] = eT2 * LOG2E; edst[rb + 3] = eT3 * LOG2E;
    }
}

// ---------------- K3: bitmask softmax (m=0) + P@H ----------------
// grid 512: ib = bx>>2 (32 rows), hh = bx&3. 8 waves = 8 j-splits of 512 j.
// Each wave: 2 row-groups (i0+row, i0+16+row) x 16 tiles of 32 j.
__device__ __forceinline__ float mask_and(float p, unsigned mw, int bit) {
    unsigned mf = (unsigned)((int)(mw << (31 - bit)) >> 31);
    return __builtin_bit_cast(float, __builtin_bit_cast(unsigned, p) & mf);
}

#define K3_MKP(AF, ES, MW, TI) {                                                  \
    float s0 = ES + E0[0], s1 = ES + E0[1], s2 = ES + E0[2], s3 = ES + E0[3];     \
    float s4 = ES + E1[0], s5 = ES + E1[1], s6 = ES + E1[2], s7 = ES + E1[3];     \
    s0 = fmaxf(s0, 0.2f * s0); s1 = fmaxf(s1, 0.2f * s1);                         \
    s2 = fmaxf(s2, 0.2f * s2); s3 = fmaxf(s3, 0.2f * s3);                         \
    s4 = fmaxf(s4, 0.2f * s4); s5 = fmaxf(s5, 0.2f * s5);                         \
    s6 = fmaxf(s6, 0.2f * s6); s7 = fmaxf(s7, 0.2f * s7);                         \
    float p0 = __builtin_exp2f(s0), p1 = __builtin_exp2f(s1);                     \
    float p2 = __builtin_exp2f(s2), p3 = __builtin_exp2f(s3);                     \
    float p4 = __builtin_exp2f(s4), p5 = __builtin_exp2f(s5);                     \
    float p6 = __builtin_exp2f(s6), p7 = __builtin_exp2f(s7);                     \
    p0 = mask_and(p0, MW, (TI) * 8 + 0); p1 = mask_and(p1, MW, (TI) * 8 + 1);     \
    p2 = mask_and(p2, MW, (TI) * 8 + 2); p3 = mask_and(p3, MW, (TI) * 8 + 3);     \
    p4 = mask_and(p4, MW, (TI) * 8 + 4); p5 = mask_and(p5, MW, (TI) * 8 + 5);     \
    p6 = mask_and(p6, MW, (TI) * 8 + 6); p7 = mask_and(p7, MW, (TI) * 8 + 7);     \
    AF[0] = (__bf16)p0; AF[1] = (__bf16)p1; AF[2] = (__bf16)p2; AF[3] = (__bf16)p3; \
    AF[4] = (__bf16)p4; AF[5] = (__bf16)p5; AF[6] = (__bf16)p6; AF[7] = (__bf16)p7; \
}

__global__ __launch_bounds__(512, 4) void k3_flash(const unsigned int* __restrict__ mb32,
                                                   const unsigned short* __restrict__ hB,
                                                   const float* __restrict__ esrc,
                                                   const float* __restrict__ edst,
                                                   float* __restrict__ out) {
    __shared__ float lacc[8][16][64];
    __shared__ float lls[8][16];

    const int lane = threadIdx.x & 63;
    const int q  = threadIdx.x >> 6;  // j-split 0..7 (512 j each)
    const int hh = blockIdx.x & 3;    // head
    const int ib = blockIdx.x >> 2;   // 0..127
    const int i0 = ib * 32;
    const int row = lane & 15;
    const int kg  = lane >> 4;

    const float es0 = esrc[hh * NN + i0 + row];
    const float es1 = esrc[hh * NN + i0 + 16 + row];
    const unsigned int* m0p = mb32 + (i0 + row) * 128 + (q >> 1) * 32 + kg * 8 + (q & 1) * 4;
    const unsigned int* m1p = m0p + 16 * 128;
    const float* eD = edst + hh * NN + q * 512 + kg * 8;
    const unsigned short* hBp = hB + ((hh * 128 + q * 16) * 256 + lane) * 8;

    // ones B-fragment: column 0 only
    u16x8 ou;
    const unsigned short ov = (row == 0) ? (unsigned short)0x3F80 : (unsigned short)0;
#pragma unroll
    for (int e = 0; e < 8; ++e) ou[e] = ov;
    const bf16x8 bOnes = __builtin_bit_cast(bf16x8, ou);

    f32x4 aA0 = (f32x4)0.f, aA1 = (f32x4)0.f, aA2 = (f32x4)0.f,
          aA3 = (f32x4)0.f, aA4 = (f32x4)0.f;
    f32x4 aB0 = (f32x4)0.f, aB1 = (f32x4)0.f, aB2 = (f32x4)0.f,
          aB3 = (f32x4)0.f, aB4 = (f32x4)0.f;

    for (int td = 0; td < 4; ++td) {
        const unsigned int M0 = m0p[td];
        const unsigned int M1 = m1p[td];
        const float* eDt = eD + td * 128;
        const unsigned short* hBt = hBp + td * 8192;
#pragma unroll
        for (int ti = 0; ti < 4; ++ti) {
            const f32x4 E0 = *(const f32x4*)(eDt + ti * 32);
            const f32x4 E1 = *(const f32x4*)(eDt + ti * 32 + 4);
            const u16x8 B0 = *(const u16x8*)(hBt + ti * 2048);
            const u16x8 B1 = *(const u16x8*)(hBt + ti * 2048 + 512);
            const u16x8 B2 = *(const u16x8*)(hBt + ti * 2048 + 1024);
            const u16x8 B3 = *(const u16x8*)(hBt + ti * 2048 + 1536);
            bf16x8 af0, af1;
            K3_MKP(af0, es0, M0, ti)
            K3_MKP(af1, es1, M1, ti)
            aA0 = __builtin_amdgcn_mfma_f32_16x16x32_bf16(af0, __builtin_bit_cast(bf16x8, B0), aA0, 0, 0, 0);
            aA1 = __builtin_amdgcn_mfma_f32_16x16x32_bf16(af0, __builtin_bit_cast(bf16x8, B1), aA1, 0, 0, 0);
            aA2 = __builtin_amdgcn_mfma_f32_16x16x32_bf16(af0, __builtin_bit_cast(bf16x8, B2), aA2, 0, 0, 0);
            aA3 = __builtin_amdgcn_mfma_f32_16x16x32_bf16(af0, __builtin_bit_cast(bf16x8, B3), aA3, 0, 0, 0);
            aA4 = __builtin_amdgcn_mfma_f32_16x16x32_bf16(af0, bOnes, aA4, 0, 0, 0);
            aB0 = __builtin_amdgcn_mfma_f32_16x16x32_bf16(af1, __builtin_bit_cast(bf16x8, B0), aB0, 0, 0, 0);
            aB1 = __builtin_amdgcn_mfma_f32_16x16x32_bf16(af1, __builtin_bit_cast(bf16x8, B1), aB1, 0, 0, 0);
            aB2 = __builtin_amdgcn_mfma_f32_16x16x32_bf16(af1, __builtin_bit_cast(bf16x8, B2), aB2, 0, 0, 0);
            aB3 = __builtin_amdgcn_mfma_f32_16x16x32_bf16(af1, __builtin_bit_cast(bf16x8, B3), aB3, 0, 0, 0);
            aB4 = __builtin_amdgcn_mfma_f32_16x16x32_bf16(af1, bOnes, aB4, 0, 0, 0);
        }
    }

    // ---- merge pass 1: row-group 0 (rows i0 .. i0+15) ----
#pragma unroll
    for (int n = 0; n < 4; ++n) {
        f32x4 an = (n == 0) ? aA0 : (n == 1) ? aA1 : (n == 2) ? aA2 : aA3;
#pragma unroll
        for (int r = 0; r < 4; ++r)
            lacc[q][kg * 4 + r][n * 16 + row] = an[r];
    }
    if (row == 0) {
#pragma unroll
        for (int r = 0; r < 4; ++r) lls[q][kg * 4 + r] = aA4[r];
    }
    __syncthreads();
    if (threadIdx.x < 256) {
        const int idx = threadIdx.x * 4;
        const int r2 = idx >> 6;
        const int c  = idx & 63;
        f32x4 v = (f32x4)0.f;
        float l = 0.f;
#pragma unroll
        for (int q2 = 0; q2 < 8; ++q2) {
            v += *(const f32x4*)&lacc[q2][r2][c];
            l += lls[q2][r2];
        }
        const float inv = 1.f / l;
        f32x4 o;
        o[0] = v[0] * inv; o[1] = v[1] * inv; o[2] = v[2] * inv; o[3] = v[3] * inv;
        *(f32x4*)(out + (i0 + r2) * 256 + hh * 64 + c) = o;
    }
    __syncthreads();

    // ---- merge pass 2: row-group 1 (rows i0+16 .. i0+31) ----
#pragma unroll
    for (int n = 0; n < 4; ++n) {
        f32x4 an = (n == 0) ? aB0 : (n == 1) ? aB1 : (n == 2) ? aB2 : aB3;
#pragma unroll
        for (int r = 0; r < 4; ++r)
            lacc[q][kg * 4 + r][n * 16 + row] = an[r];
    }
    if (row == 0) {
#pragma unroll
        for (int r = 0; r < 4; ++r) lls[q][kg * 4 + r] = aB4[r];
    }
    __syncthreads();
    if (threadIdx.x < 256) {
        const int idx = threadIdx.x * 4;
        const int r2 = idx >> 6;
        const int c  = idx & 63;
        f32x4 v = (f32x4)0.f;
        float l = 0.f;
#pragma unroll
        for (int q2 = 0; q2 < 8; ++q2) {
            v += *(const f32x4*)&lacc[q2][r2][c];
            l += lls[q2][r2];
        }
        const float inv = 1.f / l;
        f32x4 o;
        o[0] = v[0] * inv; o[1] = v[1] * inv; o[2] = v[2] * inv; o[3] = v[3] * inv;
        *(f32x4*)(out + (i0 + 16 + r2) * 256 + hh * 64 + c) = o;
    }
}

extern "C" void kernel_launch(void* const* d_in, const int* in_sizes, int n_in,
                              void* d_out, int out_size, void* d_ws, size_t ws_size,
                              hipStream_t stream) {
    const float* X    = (const float*)d_in[0];
    const int*   adj  = (const int*)d_in[1];
    const float* W    = (const float*)d_in[2];
    const float* bias = (const float*)d_in[3];
    const float* a    = (const float*)d_in[4];
    float* out = (float*)d_out;

    char* ws = (char*)d_ws;
    unsigned int*   mb   = (unsigned int*)(ws);                           // 2 MB
    unsigned short* hB   = (unsigned short*)(ws + (2 << 20));             // 2 MB
    float*          esrc = (float*)(ws + (4 << 20));                      // 64 KB (HEADS*N)
    float*          edst = (float*)(ws + (4 << 20) + (64 << 10));         // 64 KB (HEADS*N)

    k0_pack<<<2048, 256, 0, stream>>>(adj, mb);
    k1_fused<<<256, 256, 0, stream>>>(X, W, bias, a, hB, esrc, edst);
    k3_flash<<<512, 512, 0, stream>>>(mb, hB, esrc, edst, out);
}